// Round 4
// baseline (250.084 us; speedup 1.0000x reference)
//
#include <hip/hip_runtime.h>
#include <math.h>

#define NBINS 32
#define DCOLS 64
#define BLOCK 512

typedef float f32x4 __attribute__((ext_vector_type(4)));

// ws layout (float offsets)
// Packed table: float4 {A,B,C,pad} at slot k*64 + perm(d), 2048 float4 = 32KB
#define WS_TAB   0
#define WS_S     8192         // S[64] = exp(clip(logs))/100
#define WS_T     8256         // T[64] = b*exp(clip(logs))/100 + 0.5
#define WS_SUMLS 8320         // scalar sum(clip(logs))

// Column swizzle: d = 4*cg + i  ->  16*i + cg.  For a b128 read by a
// 16-lane quarter-wave (fixed i, cg=0..15): dword bank = (64i+4cg)%32 =
// 4*(cg%8) -> 2 lanes per 4-bank group = 2-way = free (m136).
__device__ __forceinline__ int swz(int d) { return ((d & 3) << 4) | (d >> 2); }

// ---------------------------------------------------------------------------
// Precompute kernel: one block, 64 threads (one per column d).
//   y    = A + B*xs + C*xs^2          (cover case)
//   dlog = B + 2C*xs = t + C*xs where t = B + C*xs
// ---------------------------------------------------------------------------
__global__ __launch_bounds__(64) void precompute_kernel(
    const float* __restrict__ p, const float* __restrict__ b,
    const float* __restrict__ logs, float* __restrict__ ws)
{
  const int d = threadIdx.x;  // column 0..63
  const int ds = swz(d);      // swizzled column slot

  double powr[17];
  {
    double rp = 1.0;
    for (int i = 0; i <= 16; i++) { powr[i] = rp; rp *= 1.2; }
  }
  const double x1L = 50.0 * 0.2 / (powr[16] - 1.0);
  float meshf[NBINS + 1];
  for (int i = 0; i <= NBINS; i++) {
    int idx = i - 16;
    int a = idx >= 0 ? idx : -idx;
    double xr = (1.0 - powr[a]) / (1.0 - 1.2);
    xr = (idx >= 0) ? x1L * xr : -x1L * xr;
    meshf[i] = (float)((xr + 50.0) / 100.0);
  }
  meshf[0] = 0.0f;
  meshf[NBINS] = 1.0f;
  float esf[NBINS];
  for (int i = 0; i < NBINS; i++) esf[i] = meshf[i + 1] - meshf[i];

  float ls = logs[d];
  ls = fminf(fmaxf(ls, -5.0f), 5.0f);
  const float s = expf(ls);
  const float bd = b[d];

  float ep[NBINS - 1];
  float denom = 0.0f;
  for (int j = 0; j < NBINS - 1; j++) {
    ep[j] = expf(p[j * DCOLS + d]);
    denom += ep[j] * ((esf[j] + esf[j + 1]) * 0.5f);
  }
  const float fnorm = (1.0f - esf[0]) / denom;
  float pdf[NBINS + 1];
  pdf[0] = 1.0f;
  pdf[NBINS] = 1.0f;
  for (int j = 0; j < NBINS - 1; j++) pdf[j + 1] = ep[j] * fnorm;

  float F = 0.0f;
  for (int k = 0; k < NBINS; k++) {
    const double v1 = (double)pdf[k];
    const double v2 = (double)pdf[k + 1];
    const double h  = (double)esf[k];
    const double m  = (double)meshf[k];
    const double c2 = 0.5 * (v2 - v1) / h;
    const double c1 = v1;
    const double A  = (double)F - c1 * m + c2 * m * m;
    const double B  = c1 - 2.0 * c2 * m;
    const int slot = (k * DCOLS + ds) * 4;
    ws[WS_TAB + slot + 0] = (float)A;
    ws[WS_TAB + slot + 1] = (float)B;
    ws[WS_TAB + slot + 2] = (float)c2;
    ws[WS_TAB + slot + 3] = 0.0f;
    const float cell = 0.5f * (pdf[k] + pdf[k + 1]) * esf[k];
    F += cell;
  }

  ws[WS_S + d] = (float)((double)s * 0.01);
  ws[WS_T + d] = (float)((double)bd * (double)s * 0.01 + 0.5);

  float sum = ls;
  for (int m = 1; m < 64; m <<= 1) sum += __shfl_xor(sum, m, 64);
  if (d == 0) ws[WS_SUMLS] = sum;
}

// ---------------------------------------------------------------------------
// Per-float4 spline evaluation; element i of lane (cg) lives at packed slot
// k*64 + 16*i + cg (one ds_read_b128 per element).
// res -> out values; lsum accumulates log2(dlog).
// ---------------------------------------------------------------------------
__device__ __forceinline__ void proc4(
    const float4 xv, const float4 S4, const float4 T4,
    const float4* __restrict__ sT, int cg, float C1, float INVL2R,
    f32x4& res, float& lsum)
{
  float xs_[4] = { fmaf(xv.x, S4.x, T4.x), fmaf(xv.y, S4.y, T4.y),
                   fmaf(xv.z, S4.z, T4.z), fmaf(xv.w, S4.w, T4.w) };
  float r_[4];
  float ls = 0.0f;
#pragma unroll
  for (int i = 0; i < 4; i++) {
    const float xs = xs_[i];
    const float a  = fabsf(xs - 0.5f);
    const float u  = __log2f(fmaf(a, C1, 1.0f)) * INVL2R;
    const float mfl = floorf(u);
    const float kf  = (xs >= 0.5f) ? (16.0f + mfl) : (15.0f - mfl);
    const int k = (int)kf;
    const bool cover = (k >= 0) && (k <= NBINS - 1);
    const int kc = k < 0 ? 0 : (k > NBINS - 1 ? NBINS - 1 : k);
    const float4 co = sT[kc * DCOLS + 16 * i + cg];   // {A,B,C,pad} b128
    const float t  = fmaf(xs, co.z, co.y);            // B + C*xs
    const float y  = cover ? fmaf(xs, t, co.x) : xs;  // A + B*xs + C*xs^2
    const float dl = fmaf(xs, co.z, t);               // B + 2C*xs
    r_[i] = fmaf(y, 100.0f, -50.0f);
    ls += cover ? __log2f(dl) : 0.0f;
  }
  res = (f32x4){r_[0], r_[1], r_[2], r_[3]};
  lsum += ls;
}

// ---------------------------------------------------------------------------
// Main kernel: 512 threads (8 waves); lane = (row-sub, col-group); float4/lane.
// 16 rows per wave-iteration.  4 blocks/CU x 8 waves = 32 waves/CU.
// ---------------------------------------------------------------------------
__global__ __launch_bounds__(BLOCK, 8) void fwd_kernel(
    const float* __restrict__ x, const float* __restrict__ logdet_in,
    const float* __restrict__ ws, float* __restrict__ out,
    float* __restrict__ logdet_out, int nrows, float C1, float INVL2R)
{
  __shared__ float4 sT[NBINS * DCOLS];        // packed {A,B,C,pad}, 32KB
  {
    const float4* wsv = (const float4*)(ws);  // WS_TAB == 0
    for (int i = threadIdx.x; i < NBINS * DCOLS; i += BLOCK)
      sT[i] = wsv[i];
  }
  const int lane = threadIdx.x & 63;
  const int wid  = threadIdx.x >> 6;   // wave in block 0..7
  const int cg   = lane & 15;          // column group 0..15
  const int rs   = lane >> 4;          // row sub 0..3
  const int c0   = cg * 4;
  const float4 S4 = *(const float4*)(ws + WS_S + c0);
  const float4 T4 = *(const float4*)(ws + WS_T + c0);
  const float sumls = ws[WS_SUMLS];
  __syncthreads();

  const int gw = blockIdx.x * 8 + wid;
  const int nw = gridDim.x * 8;

  for (int r0 = gw * 16; r0 < nrows; r0 += nw * 16) {
    const int rA = r0 + rs;
    const int rB = r0 + 4 + rs;
    const int rC = r0 + 8 + rs;
    const int rD = r0 + 12 + rs;
    const float4 xA = *(const float4*)(x + (size_t)rA * DCOLS + c0);
    const float4 xB = *(const float4*)(x + (size_t)rB * DCOLS + c0);
    const float4 xC = *(const float4*)(x + (size_t)rC * DCOLS + c0);
    const float4 xD = *(const float4*)(x + (size_t)rD * DCOLS + c0);

    f32x4 res;
    float lA = 0.0f, lB = 0.0f, lC = 0.0f, lD = 0.0f;
    proc4(xA, S4, T4, sT, cg, C1, INVL2R, res, lA);
    __builtin_nontemporal_store(res, (f32x4*)(out + (size_t)rA * DCOLS + c0));
    proc4(xB, S4, T4, sT, cg, C1, INVL2R, res, lB);
    __builtin_nontemporal_store(res, (f32x4*)(out + (size_t)rB * DCOLS + c0));
    proc4(xC, S4, T4, sT, cg, C1, INVL2R, res, lC);
    __builtin_nontemporal_store(res, (f32x4*)(out + (size_t)rC * DCOLS + c0));
    proc4(xD, S4, T4, sT, cg, C1, INVL2R, res, lD);
    __builtin_nontemporal_store(res, (f32x4*)(out + (size_t)rD * DCOLS + c0));

    // sum of log2(dlog) over the 16 lanes of each row group
#pragma unroll
    for (int m = 1; m < 16; m <<= 1) {
      lA += __shfl_xor(lA, m, 64);
      lB += __shfl_xor(lB, m, 64);
      lC += __shfl_xor(lC, m, 64);
      lD += __shfl_xor(lD, m, 64);
    }
    if (cg == 0) {
      const float LN2 = 0.6931471805599453f;
      logdet_out[rA] = logdet_in[rA] + sumls + LN2 * lA;
      logdet_out[rB] = logdet_in[rB] + sumls + LN2 * lB;
      logdet_out[rC] = logdet_in[rC] + sumls + LN2 * lC;
      logdet_out[rD] = logdet_in[rD] + sumls + LN2 * lD;
    }
  }
}

extern "C" void kernel_launch(void* const* d_in, const int* in_sizes, int n_in,
                              void* d_out, int out_size, void* d_ws, size_t ws_size,
                              hipStream_t stream) {
  const float* x      = (const float*)d_in[0];
  const float* logdet = (const float*)d_in[1];
  const float* p      = (const float*)d_in[2];
  const float* b      = (const float*)d_in[3];
  const float* logs   = (const float*)d_in[4];
  float* out = (float*)d_out;
  float* ws  = (float*)d_ws;

  const int N = in_sizes[0] / DCOLS;           // 524288
  float* logdet_out = out + (size_t)N * DCOLS;

  precompute_kernel<<<1, 64, 0, stream>>>(p, b, logs, ws);

  double Rm = 1.0;
  for (int i = 0; i < 16; i++) Rm *= 1.2;
  const double x1L = 50.0 * (1.2 - 1.0) / (Rm - 1.0);
  const double X1L = x1L / 100.0;
  const float C1      = (float)((1.2 - 1.0) / X1L);
  const float INVL2R  = (float)(1.0 / log2(1.2));

  // 1024 blocks x 512 threads: exactly 4 blocks/CU, 4 grid-stride iters.
  const int grid = 1024;
  fwd_kernel<<<grid, BLOCK, 0, stream>>>(x, logdet, ws, out, logdet_out, N,
                                         C1, INVL2R);
}